// Round 3
// baseline (268.325 us; speedup 1.0000x reference)
//
#include <hip/hip_runtime.h>
#include <math.h>

// SymmetryLoss: 3 plane reflections + 3 quaternion rotations of 1e6 points,
// nearest-grid-point distance (256^3x3 grid gather), plus tiny 3x3 regularizer.
// Scatter-latency/line-traffic bound on random 12B gathers into the 201MB grid.
// R3: dwordx3 gathers (12B struct), 2 batches of 12 gathers -> lower VGPR,
//     higher occupancy.

#define RGRID 256
#define PTS_PER_THREAD 4

struct g3 { float x, y, z; };   // 12B, naturally 4-aligned -> global_load_dwordx3

__global__ void __launch_bounds__(256)
symloss_main(const float* __restrict__ planes, const float* __restrict__ axes,
             const float* __restrict__ pts, const float* __restrict__ grid,
             const float* __restrict__ gmin, const float* __restrict__ gmax,
             float* __restrict__ acc, int N) {
    // Uniform-address parameter loads -> scalar loads
    float P[12], Q[12];
#pragma unroll
    for (int i = 0; i < 12; ++i) { P[i] = planes[i]; Q[i] = axes[i]; }
    const float g0 = gmin[0], g1 = gmin[1], g2 = gmin[2];
    const float s0 = 255.0f / (gmax[0] - g0);
    const float s1 = 255.0f / (gmax[1] - g1);
    const float s2 = 255.0f / (gmax[2] - g2);

    const g3* __restrict__ gridc = (const g3*)grid;

    const int t  = blockIdx.x * blockDim.x + threadIdx.x;
    const int p0 = t * PTS_PER_THREAD;

    float lsum = 0.0f;
    if (p0 < N) {
        float px[4], py[4], pz[4];
        int npts;
        if (p0 + 3 < N) {
            // 4 points = 12 floats = 3 aligned float4 loads
            const float4* pts4 = (const float4*)pts;
            float4 a = pts4[3 * t + 0];
            float4 b = pts4[3 * t + 1];
            float4 c = pts4[3 * t + 2];
            px[0] = a.x; py[0] = a.y; pz[0] = a.z;
            px[1] = a.w; py[1] = b.x; pz[1] = b.y;
            px[2] = b.z; py[2] = b.w; pz[2] = c.x;
            px[3] = c.y; py[3] = c.z; pz[3] = c.w;
            npts = 4;
        } else {
            npts = N - p0;
#pragma unroll
            for (int i = 0; i < 4; ++i) {
                int p = p0 + (i < npts ? i : 0);   // clamped dup, masked below
                px[i] = pts[3 * p + 0];
                py[i] = pts[3 * p + 1];
                pz[i] = pts[3 * p + 2];
            }
        }

        float partial[4] = {0.0f, 0.0f, 0.0f, 0.0f};

        // 2 batches x 2 points x 6 transforms = 12 in-flight gathers/batch.
        // Smaller live range -> ~half the VGPRs of a single 24-gather batch.
#pragma unroll
        for (int half = 0; half < 2; ++half) {
            float tx[12], ty[12], tz[12];
#pragma unroll
            for (int j = 0; j < 2; ++j) {
                const int i = 2 * half + j;
                const float x = px[i], y = py[i], z = pz[i];
                // 3 plane reflections: tp = p - 2*(p.n + d)*n
#pragma unroll
                for (int k = 0; k < 3; ++k) {
                    float nx = P[4 * k + 0], ny = P[4 * k + 1], nz = P[4 * k + 2], d = P[4 * k + 3];
                    float m2p = -2.0f * (x * nx + y * ny + z * nz + d);
                    int o = j * 6 + k;
                    tx[o] = fmaf(m2p, nx, x);
                    ty[o] = fmaf(m2p, ny, y);
                    tz[o] = fmaf(m2p, nz, z);
                }
                // 3 quaternion conjugations: o = (q * (0,p) * q_conj)[1:]
#pragma unroll
                for (int k = 0; k < 3; ++k) {
                    float qw = Q[4 * k + 0], qx = Q[4 * k + 1], qy = Q[4 * k + 2], qz = Q[4 * k + 3];
                    float rw = -(qx * x + qy * y + qz * z);
                    float rx = qw * x + qy * z - qz * y;
                    float ry = qw * y - qx * z + qz * x;
                    float rz = qw * z + qx * y - qy * x;
                    int o = j * 6 + 3 + k;
                    tx[o] = -rw * qx + rx * qw - ry * qz + rz * qy;
                    ty[o] = -rw * qy + rx * qz + ry * qw - rz * qx;
                    tz[o] = -rw * qz - rx * qy + ry * qx + rz * qw;
                }
            }
            // addresses first, then 12 batched dwordx3 loads
            int cell[12];
#pragma unroll
            for (int o = 0; o < 12; ++o) {
                float f0 = rintf((tx[o] - g0) * s0);  // round-half-to-even == jnp.round
                float f1 = rintf((ty[o] - g1) * s1);
                float f2 = rintf((tz[o] - g2) * s2);
                f0 = fminf(fmaxf(f0, 0.0f), 255.0f);
                f1 = fminf(fmaxf(f1, 0.0f), 255.0f);
                f2 = fminf(fmaxf(f2, 0.0f), 255.0f);
                cell[o] = ((int)f0 * RGRID + (int)f1) * RGRID + (int)f2;
            }
#pragma unroll
            for (int o = 0; o < 12; ++o) {
                g3 c = gridc[cell[o]];
                float dx = tx[o] - c.x, dy = ty[o] - c.y, dz = tz[o] - c.z;
                partial[2 * half + o / 6] += sqrtf(fmaf(dx, dx, fmaf(dy, dy, dz * dz)));
            }
        }
#pragma unroll
        for (int i = 0; i < 4; ++i)
            if (i < npts) lsum += partial[i];
    }

    // wave(64) shuffle reduce -> LDS -> one atomic per block
#pragma unroll
    for (int off = 32; off > 0; off >>= 1)
        lsum += __shfl_down(lsum, off, 64);
    __shared__ float wsum[4];
    int lane = threadIdx.x & 63;
    int wid  = threadIdx.x >> 6;
    if (lane == 0) wsum[wid] = lsum;
    __syncthreads();
    if (threadIdx.x == 0) {
        atomicAdd(acc, wsum[0] + wsum[1] + wsum[2] + wsum[3]);
    }
}

__global__ void symloss_final(const float* __restrict__ planes,
                              const float* __restrict__ axes,
                              const float* __restrict__ acc,
                              float* __restrict__ out, float invN) {
    float sd = acc[0] * invN;

    float n[3][3];
#pragma unroll
    for (int i = 0; i < 3; ++i)
#pragma unroll
        for (int j = 0; j < 3; ++j) n[i][j] = planes[4 * i + j];

    float sA = 0.0f;
#pragma unroll
    for (int i = 0; i < 3; ++i)
#pragma unroll
        for (int j = 0; j < 3; ++j) {
            float a = n[i][0] * n[j][0] + n[i][1] * n[j][1] + n[i][2] * n[j][2]
                      - (i == j ? 1.0f : 0.0f);
            sA += a * a;
        }

    float v[3][3];
#pragma unroll
    for (int i = 0; i < 3; ++i) {
        float vx = axes[4 * i + 1], vy = axes[4 * i + 2], vz = axes[4 * i + 3];
        float nrm = sqrtf(vx * vx + vy * vy + vz * vz);
        nrm = fmaxf(nrm, 1e-12f);
        v[i][0] = vx / nrm; v[i][1] = vy / nrm; v[i][2] = vz / nrm;
    }
    float sB = 0.0f;
#pragma unroll
    for (int i = 0; i < 3; ++i)
#pragma unroll
        for (int j = 0; j < 3; ++j) {
            float b = v[i][0] * v[j][0] + v[i][1] * v[j][1] + v[i][2] * v[j][2]
                      - (i == j ? 1.0f : 0.0f);
            sB += b * b;
        }

    float r = sA + sB;
    out[0] = sd + 25.0f * r;   // final_loss
    out[1] = sd;               // total_loss_sd
    out[2] = r;                // total_loss_r
}

extern "C" void kernel_launch(void* const* d_in, const int* in_sizes, int n_in,
                              void* d_out, int out_size, void* d_ws, size_t ws_size,
                              hipStream_t stream) {
    const float* planes = (const float*)d_in[0];   // (1,3,4)
    const float* axes   = (const float*)d_in[1];   // (1,3,4)
    const float* pts    = (const float*)d_in[2];   // (N,3)
    const float* grid   = (const float*)d_in[3];   // (256,256,256,3)
    const float* gmin   = (const float*)d_in[4];   // (3,)
    const float* gmax   = (const float*)d_in[5];   // (3,)
    float* out = (float*)d_out;
    float* acc = (float*)d_ws;

    int N = in_sizes[2] / 3;

    hipMemsetAsync(acc, 0, sizeof(float), stream);

    int nthreads = (N + PTS_PER_THREAD - 1) / PTS_PER_THREAD;
    int blocks = (nthreads + 255) / 256;
    hipLaunchKernelGGL(symloss_main, dim3(blocks), dim3(256), 0, stream,
                       planes, axes, pts, grid, gmin, gmax, acc, N);
    hipLaunchKernelGGL(symloss_final, dim3(1), dim3(1), 0, stream,
                       planes, axes, acc, out, 1.0f / (float)N);
}